// Round 4
// baseline (3491.714 us; speedup 1.0000x reference)
//
#include <hip/hip_runtime.h>
#include <math.h>

#define NA   360
#define VDET 256
#define UDET 256
#define NZ   128
#define NY   128
#define NX   128
#define ZPT  8    // z-slices per thread

// Geometry: dz=dy=dx=2mm, dv=du=2mm, DSO=1000, DSD=1536.
// iv = (zidx-63.5)*mag + 127.5, mag in [1.30,1.88] -> iv in (8.6,246.4):
//   v never clamps, v0+1 always in-bounds.
// iu needs validity/clamp; uniform over z, folded into u-weights (branchless).
//
// R4: software-pipeline across angles (issue a+1's gathers before combining a)
// to keep gathers in flight ~always; 32-bit saddr offsets; 6-op bilinear.

struct Ang {
    float mag, ivb, wu0, wu1;
    uint32_t base;   // byte offset of (a, v=0, u0) within batch slab
};

__device__ __forceinline__ Ang ang_setup(int a, const float2* cs_sh,
                                         float xc, float yc, float zf0) {
    const float2 sc = cs_sh[a];
    const float c = sc.x, s = sc.y;
    const float xr  = xc * c + yc * s;
    const float yr  = yc * c - xc * s;
    Ang g;
    g.mag = 1536.0f * __builtin_amdgcn_rcpf(1000.0f - xr);
    const float iu  = fmaf(yr * g.mag, 0.5f, 127.5f);
    const bool uval = (iu >= 0.0f) && (iu <= 255.0f);
    const float iuc = fminf(fmaxf(iu, 0.0f), 255.0f);
    int u0 = (int)iuc;
    u0 = u0 > (UDET - 2) ? (UDET - 2) : u0;
    const float fu = iuc - (float)u0;
    const float w  = uval ? 1.0f : 0.0f;
    g.wu1 = fu * w;
    g.wu0 = w - g.wu1;
    g.ivb = fmaf(zf0, g.mag, 127.5f);
    g.base = ((uint32_t)a << 18) + ((uint32_t)u0 << 2);
    return g;
}

__device__ __forceinline__ void ang_issue(const Ang& g, const char* projB,
                                          float fv[ZPT], float2 q0[ZPT], float2 q1[ZPT]) {
    #pragma unroll
    for (int k = 0; k < ZPT; ++k) {
        const float iv = fmaf((float)k, g.mag, g.ivb);
        const int v0 = (int)iv;              // iv > 0 -> trunc == floor
        fv[k] = iv - (float)v0;
        const char* p = projB + (g.base + ((uint32_t)v0 << 10));
        q0[k] = *reinterpret_cast<const float2*>(p);          // row v0: u0,u0+1
        q1[k] = *reinterpret_cast<const float2*>(p + 1024);   // row v0+1
    }
}

__device__ __forceinline__ void ang_combine(const Ang& g, const float fv[ZPT],
                                            const float2 q0[ZPT], const float2 q1[ZPT],
                                            float acc[ZPT]) {
    #pragma unroll
    for (int k = 0; k < ZPT; ++k) {
        const float b0 = fmaf(fv[k], q1[k].x - q0[k].x, q0[k].x);
        const float b1 = fmaf(fv[k], q1[k].y - q0[k].y, q0[k].y);
        acc[k] = fmaf(g.wu0, b0, acc[k]);
        acc[k] = fmaf(g.wu1, b1, acc[k]);
    }
}

__global__ __launch_bounds__(256, 4) void bp_kernel(const float* __restrict__ proj,
                                                    float* __restrict__ out) {
    __shared__ float2 cs_sh[NA];
    const int tid = threadIdx.y * 16 + threadIdx.x;
    for (int i = tid; i < NA; i += 256) {
        float th = (float)i * (float)(2.0 * M_PI / (double)NA);
        float sv, cv;
        sincosf(th, &sv, &cv);
        cs_sh[i] = make_float2(cv, sv);
    }
    __syncthreads();

    const int x  = (blockIdx.x & 7) * 16 + threadIdx.x;   // 0..127
    const int y  = (blockIdx.x >> 3) * 16 + threadIdx.y;  // 0..127
    const int zb = blockIdx.y * ZPT;                      // z base
    const int b  = blockIdx.z;

    const float xc  = ((float)x - 63.5f) * 2.0f;
    const float yc  = ((float)y - 63.5f) * 2.0f;
    const float zf0 = (float)zb - 63.5f;

    const char* projB = (const char*)(proj + (size_t)b * NA * VDET * UDET);

    float acc[ZPT];
    #pragma unroll
    for (int k = 0; k < ZPT; ++k) acc[k] = 0.0f;

    // Software pipeline: A holds angle a (already issued), B holds a+1.
    float  fvA[ZPT], fvB[ZPT];
    float2 q0A[ZPT], q1A[ZPT], q0B[ZPT], q1B[ZPT];

    Ang gA = ang_setup(0, cs_sh, xc, yc, zf0);
    ang_issue(gA, projB, fvA, q0A, q1A);
    Ang gB;

    for (int a = 0; a < NA; a += 2) {
        gB = ang_setup(a + 1, cs_sh, xc, yc, zf0);
        ang_issue(gB, projB, fvB, q0B, q1B);
        ang_combine(gA, fvA, q0A, q1A, acc);
        if (a + 2 < NA) {
            gA = ang_setup(a + 2, cs_sh, xc, yc, zf0);
            ang_issue(gA, projB, fvA, q0A, q1A);
        }
        ang_combine(gB, fvB, q0B, q1B, acc);
    }

    float* o = out + (((size_t)b * NZ + zb) * NY + y) * NX + x;
    #pragma unroll
    for (int k = 0; k < ZPT; ++k) {
        o[(size_t)k * (NY * NX)] = acc[k];
    }
}

extern "C" void kernel_launch(void* const* d_in, const int* in_sizes, int n_in,
                              void* d_out, int out_size, void* d_ws, size_t ws_size,
                              hipStream_t stream) {
    const float* proj = (const float*)d_in[0];
    float* out = (float*)d_out;
    dim3 grid(64, NZ / ZPT, 2);   // (xy-tiles, z-groups, batch) = 2048 blocks
    dim3 block(16, 16, 1);
    hipLaunchKernelGGL(bp_kernel, grid, block, 0, stream, proj, out);
}